// Round 7
// baseline (1951.401 us; speedup 1.0000x reference)
//
#include <hip/hip_runtime.h>

#define DIMS 1024
#define NB 1024         // pass-kernel blocks
#define TPB 256
#define NWAVE 4
#define CB 64           // combine blocks (fallback path)
#define ACC_STRIDE 1088 // per-step accumulator stride (1024 dims + l + pad)

#if defined(__has_builtin)
#if __has_builtin(__builtin_amdgcn_sdot8)
#define HAVE_SDOT8 1
#endif
#endif
#ifndef HAVE_SDOT8
#define HAVE_SDOT8 0
#endif

__device__ __forceinline__ float wave_sum(float v) {
#pragma unroll
  for (int s = 32; s; s >>= 1) v += __shfl_xor(v, s, 64);
  return v;
}

__device__ __forceinline__ float wave_max(float v) {
#pragma unroll
  for (int s = 32; s; s >>= 1) v = fmaxf(v, __shfl_xor(v, s, 64));
  return v;
}

// sum within 32-lane halves (xor 16..1); result broadcast within each half
__device__ __forceinline__ int half_sum_i(int v) {
#pragma unroll
  for (int s = 16; s; s >>= 1) v += __shfl_xor(v, s, 64);
  return v;
}

__device__ __forceinline__ int nib(unsigned int w, int i) {
  return (int)(w << (28 - 4 * i)) >> 28;
}

// encode 16 f32 (4x float4, qx-order) -> 16 signed int4 nibbles in uint2
__device__ __forceinline__ uint2 enc_i4(const float4* xv, float scale) {
  unsigned int w[2];
#pragma unroll
  for (int h = 0; h < 2; ++h) {
    unsigned int a = 0;
#pragma unroll
    for (int jj = 0; jj < 2; ++jj) {
      float4 t = xv[h * 2 + jj];
      a |= ((unsigned int)((int)rintf(t.x * scale) & 0xF)) << (jj * 16 + 0);
      a |= ((unsigned int)((int)rintf(t.y * scale) & 0xF)) << (jj * 16 + 4);
      a |= ((unsigned int)((int)rintf(t.z * scale) & 0xF)) << (jj * 16 + 8);
      a |= ((unsigned int)((int)rintf(t.w * scale) & 0xF)) << (jj * 16 + 12);
    }
    w[h] = a;
  }
  return make_uint2(w[0], w[1]);
}

// ---------------- f32 pass: fixed-offset softmax, p = exp(sim-1) ----------
// STEP0: compute invnorm.  MODE: 0 = fallback (part_acc/part_l), 1 = quant-write + atomic acc0.
template <int STEP0, int MODE>
__global__ __launch_bounds__(TPB) void pass_f32(
    const float* __restrict__ ca3,
    const float* __restrict__ q,        // cur0 buffer
    float* __restrict__ invnorm,
    uint2* __restrict__ qmat,
    float2* __restrict__ rowmeta,
    float* __restrict__ accbuf,         // MODE=1: acc_0 (atomic)
    float* __restrict__ part_acc,       // MODE=0
    float* __restrict__ part_l,         // MODE=0
    int rows_per_block) {
  const int tid  = threadIdx.x;
  const int lane = tid & 63;
  const int wv   = tid >> 6;
  const int bid  = blockIdx.x;

  const float4* q4 = (const float4*)q;
  float4 qv[4];
  float qss = 0.f;
#pragma unroll
  for (int j = 0; j < 4; ++j) {
    float4 t = q4[j * 64 + lane];
    qv[j] = t;
    qss += t.x * t.x + t.y * t.y + t.z * t.z + t.w * t.w;
  }
  qss = wave_sum(qss);
  const float inv_qn = 1.0f / fmaxf(sqrtf(qss), 1e-8f);

  const int rpw = rows_per_block >> 2;
  const long long row0 = (long long)bid * rows_per_block + (long long)wv * rpw;

  float l = 0.f;
  float4 acc[4];
#pragma unroll
  for (int j = 0; j < 4; ++j) acc[j] = make_float4(0.f, 0.f, 0.f, 0.f);

  for (int r = 0; r < rpw; r += 2) {
    const long long rowA = row0 + r;
    const long long rowB = rowA + 1;
    const float4* xA4 = (const float4*)(ca3 + rowA * (long long)DIMS);
    const float4* xB4 = (const float4*)(ca3 + rowB * (long long)DIMS);
    float innA = 0.f, innB = 0.f;
    if (!STEP0) { innA = invnorm[rowA]; innB = invnorm[rowB]; }
    float4 xa[4], xb[4];
#pragma unroll
    for (int j = 0; j < 4; ++j) xa[j] = xA4[j * 64 + lane];
#pragma unroll
    for (int j = 0; j < 4; ++j) xb[j] = xB4[j * 64 + lane];

    float dA = 0.f, dB = 0.f, rnA = 0.f, rnB = 0.f, mxA = 0.f, mxB = 0.f;
#pragma unroll
    for (int j = 0; j < 4; ++j) {
      dA += xa[j].x * qv[j].x + xa[j].y * qv[j].y + xa[j].z * qv[j].z + xa[j].w * qv[j].w;
      dB += xb[j].x * qv[j].x + xb[j].y * qv[j].y + xb[j].z * qv[j].z + xb[j].w * qv[j].w;
      if (STEP0) {
        rnA += xa[j].x * xa[j].x + xa[j].y * xa[j].y + xa[j].z * xa[j].z + xa[j].w * xa[j].w;
        rnB += xb[j].x * xb[j].x + xb[j].y * xb[j].y + xb[j].z * xb[j].z + xb[j].w * xb[j].w;
      }
      if (MODE) {
        mxA = fmaxf(mxA, fmaxf(fmaxf(fabsf(xa[j].x), fabsf(xa[j].y)),
                               fmaxf(fabsf(xa[j].z), fabsf(xa[j].w))));
        mxB = fmaxf(mxB, fmaxf(fmaxf(fabsf(xb[j].x), fabsf(xb[j].y)),
                               fmaxf(fabsf(xb[j].z), fabsf(xb[j].w))));
      }
    }
    dA = wave_sum(dA);
    dB = wave_sum(dB);
    if (STEP0) {
      rnA = wave_sum(rnA);
      rnB = wave_sum(rnB);
      innA = 1.0f / fmaxf(sqrtf(rnA), 1e-8f);
      innB = 1.0f / fmaxf(sqrtf(rnB), 1e-8f);
      if (lane == 0) { invnorm[rowA] = innA; invnorm[rowB] = innB; }
    }
    if (MODE) {
      mxA = wave_max(mxA);
      mxB = wave_max(mxB);
      const float scA = 7.0f / fmaxf(mxA, 1e-20f);
      const float scB = 7.0f / fmaxf(mxB, 1e-20f);
      qmat[rowA * 64 + lane] = enc_i4(xa, scA);
      qmat[rowB * 64 + lane] = enc_i4(xb, scB);
      if (lane == 0) {
        const float isA = mxA * (1.0f / 7.0f);
        const float isB = mxB * (1.0f / 7.0f);
        rowmeta[rowA] = make_float2(isA * innA, isA);
        rowmeta[rowB] = make_float2(isB * innB, isB);
      }
    }
    const float pA = __expf(dA * innA * inv_qn - 1.0f);
    const float pB = __expf(dB * innB * inv_qn - 1.0f);
    l += pA + pB;
#pragma unroll
    for (int j = 0; j < 4; ++j) {
      acc[j].x += pA * xa[j].x + pB * xb[j].x;
      acc[j].y += pA * xa[j].y + pB * xb[j].y;
      acc[j].z += pA * xa[j].z + pB * xb[j].z;
      acc[j].w += pA * xa[j].w + pB * xb[j].w;
    }
  }

  // ---- block combine ----
  __shared__ float s_l[NWAVE];
  __shared__ float s_lin[NWAVE * DIMS];  // 16 KB
  if (lane == 0) s_l[wv] = l;
#pragma unroll
  for (int j = 0; j < 4; ++j)
    ((float4*)s_lin)[wv * (DIMS / 4) + j * 64 + lane] = acc[j];
  __syncthreads();
  float4 sum = ((float4*)s_lin)[tid];
#pragma unroll
  for (int w = 1; w < NWAVE; ++w) {
    float4 b = ((float4*)s_lin)[w * (DIMS / 4) + tid];
    sum.x += b.x; sum.y += b.y; sum.z += b.z; sum.w += b.w;
  }
  if (MODE) {
    atomicAdd(&accbuf[4 * tid + 0], sum.x);
    atomicAdd(&accbuf[4 * tid + 1], sum.y);
    atomicAdd(&accbuf[4 * tid + 2], sum.z);
    atomicAdd(&accbuf[4 * tid + 3], sum.w);
    if (tid == 0) atomicAdd(&accbuf[1024], s_l[0] + s_l[1] + s_l[2] + s_l[3]);
  } else {
    ((float4*)part_acc)[bid * (DIMS / 4) + tid] = sum;
    if (tid == 0) part_l[bid] = s_l[0] + s_l[1] + s_l[2] + s_l[3];
  }
}

// ---------------- int4 pass: row-pair uint4 loads, half-wave reduction, atomic acc ----
__device__ __forceinline__ void process4(const uint4* u, const float2* m, uint4 qr,
                                         float qscale, float& l, int* acc_i) {
  int d[4];
#pragma unroll
  for (int k = 0; k < 4; ++k) {
#if HAVE_SDOT8
    int t = __builtin_amdgcn_sdot8((int)u[k].x, (int)qr.x, 0, false);
    t = __builtin_amdgcn_sdot8((int)u[k].y, (int)qr.y, t, false);
    t = __builtin_amdgcn_sdot8((int)u[k].z, (int)qr.z, t, false);
    t = __builtin_amdgcn_sdot8((int)u[k].w, (int)qr.w, t, false);
#else
    int t = 0;
#pragma unroll
    for (int i = 0; i < 8; ++i) t += __mul24(nib(u[k].x, i), nib(qr.x, i));
#pragma unroll
    for (int i = 0; i < 8; ++i) t += __mul24(nib(u[k].y, i), nib(qr.y, i));
#pragma unroll
    for (int i = 0; i < 8; ++i) t += __mul24(nib(u[k].z, i), nib(qr.z, i));
#pragma unroll
    for (int i = 0; i < 8; ++i) t += __mul24(nib(u[k].w, i), nib(qr.w, i));
#endif
    d[k] = t;
  }
#pragma unroll
  for (int k = 0; k < 4; ++k) d[k] = half_sum_i(d[k]);
#pragma unroll
  for (int k = 0; k < 4; ++k) {
    const float p = __expf((float)d[k] * m[k].x * qscale - 1.0f);
    l += p;
    const int pai = (int)(p * m[k].y * 1048576.0f + 0.5f);  // < 2^24
#pragma unroll
    for (int i = 0; i < 8; ++i) acc_i[i]      += __mul24(pai, nib(u[k].x, i));
#pragma unroll
    for (int i = 0; i < 8; ++i) acc_i[8 + i]  += __mul24(pai, nib(u[k].y, i));
#pragma unroll
    for (int i = 0; i < 8; ++i) acc_i[16 + i] += __mul24(pai, nib(u[k].z, i));
#pragma unroll
    for (int i = 0; i < 8; ++i) acc_i[24 + i] += __mul24(pai, nib(u[k].w, i));
  }
}

__global__ __launch_bounds__(TPB, 4) void pass_i4(
    const uint4* __restrict__ qmat4,    // pair (2 rows) = 64 uint4 (1024 B)
    const float* __restrict__ cur0,
    const float2* __restrict__ rowmeta, // {inv_scale*invnorm, inv_scale}
    float* __restrict__ accbuf,
    int step,                           // s in 1..4: read acc_0..s-1, write acc_s
    int rows_per_block) {
  const int tid  = threadIdx.x;
  const int lane = tid & 63;
  const int wv   = tid >> 6;
  const int bid  = blockIdx.x;
  const int h    = (lane >= 32) ? 1 : 0;

  __shared__ uint4 s_qpk4[32];
  __shared__ float s_qscale;

  // ---- prologue (wave 0): reconstruct cur_step, quantize q into LDS ----
  if (wv == 0) {
    float c[16];
    float w0 = 1.0f;
    for (int t = 0; t < step; ++t) w0 *= 0.2f;
    const float4* c04 = (const float4*)cur0;
#pragma unroll
    for (int jj = 0; jj < 4; ++jj) {
      float4 t = c04[jj * 64 + lane];
      c[4 * jj + 0] = w0 * t.x; c[4 * jj + 1] = w0 * t.y;
      c[4 * jj + 2] = w0 * t.z; c[4 * jj + 3] = w0 * t.w;
    }
    for (int j = 0; j < step; ++j) {
      const float lj = accbuf[j * ACC_STRIDE + 1024];
      float coef = 0.8f / lj;
      for (int t = j; t < step - 1; ++t) coef *= 0.2f;
      const float4* aj = (const float4*)(accbuf + j * ACC_STRIDE);
#pragma unroll
      for (int jj = 0; jj < 4; ++jj) {
        float4 t = aj[jj * 64 + lane];
        c[4 * jj + 0] += coef * t.x; c[4 * jj + 1] += coef * t.y;
        c[4 * jj + 2] += coef * t.z; c[4 * jj + 3] += coef * t.w;
      }
    }
    float qss = 0.f, qmx = 0.f;
#pragma unroll
    for (int i = 0; i < 16; ++i) { qss += c[i] * c[i]; qmx = fmaxf(qmx, fabsf(c[i])); }
    qss = wave_sum(qss);
    qmx = wave_max(qmx);
    const float inv_qn = 1.0f / fmaxf(sqrtf(qss), 1e-8f);
    const float sq = 7.0f / fmaxf(qmx, 1e-20f);
    unsigned int qq0 = 0, qq1 = 0;
#pragma unroll
    for (int i = 0; i < 8; ++i)
      qq0 |= ((unsigned int)((int)rintf(c[i] * sq) & 0xF)) << (4 * i);
#pragma unroll
    for (int i = 0; i < 8; ++i)
      qq1 |= ((unsigned int)((int)rintf(c[8 + i] * sq) & 0xF)) << (4 * i);
    ((uint2*)s_qpk4)[lane] = make_uint2(qq0, qq1);
    if (lane == 0) s_qscale = (qmx * (1.0f / 7.0f)) * inv_qn;
  }
  __syncthreads();
  const uint4 qr = s_qpk4[lane & 31];
  const float qscale = s_qscale;

  // ---- main loop: 32 pairs per wave, groups of 4 pairs, A/B prefetch ----
  const int ppw = rows_per_block >> 3;  // pairs per wave (32)
  const long long pair0 = ((long long)bid * rows_per_block + (long long)wv * (rows_per_block >> 2)) >> 1;
  const uint4* base = qmat4 + pair0 * 64;
  const float2* metab = rowmeta + pair0 * 2;

  float l = 0.f;
  int acc_i[32];
#pragma unroll
  for (int i = 0; i < 32; ++i) acc_i[i] = 0;

  uint4 ua[4], ub[4];
  float2 ma[4], mb[4];
#pragma unroll
  for (int k = 0; k < 4; ++k) { ua[k] = base[k * 64 + lane]; ma[k] = metab[k * 2 + h]; }

  const int ngrp = ppw >> 2;  // 8 groups of 4 pairs
  for (int g = 0; g < ngrp; g += 2) {
    const int gB = g + 1;
    const int gA2 = (g + 2 < ngrp) ? (g + 2) : 0;
#pragma unroll
    for (int k = 0; k < 4; ++k) {
      ub[k] = base[(gB * 4 + k) * 64 + lane];
      mb[k] = metab[(gB * 4 + k) * 2 + h];
    }
    process4(ua, ma, qr, qscale, l, acc_i);
#pragma unroll
    for (int k = 0; k < 4; ++k) {
      ua[k] = base[(gA2 * 4 + k) * 64 + lane];
      ma[k] = metab[(gA2 * 4 + k) * 2 + h];
    }
    process4(ub, mb, qr, qscale, l, acc_i);
  }

  // ---- epilogue: 8 fragments -> block sum -> atomic into acc_step ----
  l = wave_sum(l) * 0.03125f;  // every lane of a half held the same p -> /32
  __shared__ float s_l[NWAVE];
  __shared__ float s_lin[2 * NWAVE * DIMS];  // 32 KB
  if (lane == 0) s_l[wv] = l;
  const int f = wv * 2 + h;
  const int vl0 = 2 * (lane & 31), vl1 = vl0 + 1;
  const float ds = 9.5367431640625e-7f;  // 2^-20
#pragma unroll
  for (int jj = 0; jj < 4; ++jj) {
    ((float4*)s_lin)[f * (DIMS / 4) + jj * 64 + vl0] =
        make_float4((float)acc_i[4 * jj + 0] * ds, (float)acc_i[4 * jj + 1] * ds,
                    (float)acc_i[4 * jj + 2] * ds, (float)acc_i[4 * jj + 3] * ds);
    ((float4*)s_lin)[f * (DIMS / 4) + jj * 64 + vl1] =
        make_float4((float)acc_i[16 + 4 * jj + 0] * ds, (float)acc_i[16 + 4 * jj + 1] * ds,
                    (float)acc_i[16 + 4 * jj + 2] * ds, (float)acc_i[16 + 4 * jj + 3] * ds);
  }
  __syncthreads();
  float4 sum = ((float4*)s_lin)[tid];
#pragma unroll
  for (int w = 1; w < 2 * NWAVE; ++w) {
    float4 b = ((float4*)s_lin)[w * (DIMS / 4) + tid];
    sum.x += b.x; sum.y += b.y; sum.z += b.z; sum.w += b.w;
  }
  float* accS = accbuf + step * ACC_STRIDE;
  atomicAdd(&accS[4 * tid + 0], sum.x);
  atomicAdd(&accS[4 * tid + 1], sum.y);
  atomicAdd(&accS[4 * tid + 2], sum.z);
  atomicAdd(&accS[4 * tid + 3], sum.w);
  if (tid == 0) atomicAdd(&accS[1024], s_l[0] + s_l[1] + s_l[2] + s_l[3]);
}

// ---------------- init: zero acc buffers + DG thresholding into cur0 ----------------
__global__ void init_k(const float* __restrict__ iso, float* __restrict__ accbuf) {
  const int idx = blockIdx.x * blockDim.x + threadIdx.x;
  const int nacc = 5 * ACC_STRIDE;
  if (idx < nacc) accbuf[idx] = 0.f;
  else if (idx < nacc + DIMS) {
    const float v = iso[idx - nacc];
    accbuf[idx] = (v > 0.1f) ? v : 0.f;  // cur0 lives right after accbuf
  }
}

// ---------------- final (fast path): reconstruct cur_5, write out + mismatch ----------
__global__ __launch_bounds__(64) void final_k5(const float* __restrict__ iso,
                                               const float* __restrict__ cur0,
                                               const float* __restrict__ accbuf,
                                               float* __restrict__ out) {
  const int lane = threadIdx.x;
  float c[16];
  float w0 = 1.0f;
  for (int t = 0; t < 5; ++t) w0 *= 0.2f;
  const float4* c04 = (const float4*)cur0;
#pragma unroll
  for (int jj = 0; jj < 4; ++jj) {
    float4 t = c04[jj * 64 + lane];
    c[4 * jj + 0] = w0 * t.x; c[4 * jj + 1] = w0 * t.y;
    c[4 * jj + 2] = w0 * t.z; c[4 * jj + 3] = w0 * t.w;
  }
  for (int j = 0; j < 5; ++j) {
    const float lj = accbuf[j * ACC_STRIDE + 1024];
    float coef = 0.8f / lj;
    for (int t = j; t < 4; ++t) coef *= 0.2f;
    const float4* aj = (const float4*)(accbuf + j * ACC_STRIDE);
#pragma unroll
    for (int jj = 0; jj < 4; ++jj) {
      float4 t = aj[jj * 64 + lane];
      c[4 * jj + 0] += coef * t.x; c[4 * jj + 1] += coef * t.y;
      c[4 * jj + 2] += coef * t.z; c[4 * jj + 3] += coef * t.w;
    }
  }
  float ss = 0.f;
#pragma unroll
  for (int jj = 0; jj < 4; ++jj)
#pragma unroll
    for (int i = 0; i < 4; ++i) {
      const int d = 4 * (jj * 64 + lane) + i;
      const float cv = c[4 * jj + i];
      out[d] = cv;
      const float df = iso[d] - cv;
      ss += df * df;
    }
  ss = wave_sum(ss);
  if (lane == 0) out[DIMS] = ss * (1.0f / (float)DIMS);
}

// ---------------- fallback combine + final (unchanged structure) ----------------
__global__ __launch_bounds__(256) void combine_k(
    const float* __restrict__ part_acc,
    const float* __restrict__ part_l,
    float* __restrict__ cur) {
  const int tid  = threadIdx.x;
  const int lane = tid & 63;
  const int wv   = tid >> 6;
  __shared__ float s_w[NWAVE];
  float lz = 0.f;
  for (int p = tid; p < NB; p += 256) lz += part_l[p];
  lz = wave_sum(lz);
  if (lane == 0) s_w[wv] = lz;
  __syncthreads();
  const float invZ = 1.0f / (s_w[0] + s_w[1] + s_w[2] + s_w[3]);
  const int base = blockIdx.x * 16;
  const int d = tid & 15;
  const int g = tid >> 4;
  float a = 0.f;
  for (int p = g; p < NB; p += 16) a += part_acc[p * DIMS + base + d];
  __shared__ float s_a[16][17];
  s_a[g][d] = a;
  __syncthreads();
#pragma unroll
  for (int s = 8; s; s >>= 1) {
    if (g < s) s_a[g][d] += s_a[g + s][d];
    __syncthreads();
  }
  if (tid < 16) {
    const float retrieved = s_a[0][tid] * invZ;
    const float cc = cur[base + tid];
    cur[base + tid] = 0.8f * retrieved + 0.2f * cc;
  }
}

__global__ __launch_bounds__(256) void final_k(const float* __restrict__ iso,
                                               const float* __restrict__ cur,
                                               float* __restrict__ out) {
  const int tid  = threadIdx.x;
  const int lane = tid & 63;
  const int wv   = tid >> 6;
  float ss = 0.f;
  for (int d = tid; d < DIMS; d += 256) {
    const float c = cur[d];
    out[d] = c;
    const float df = iso[d] - c;
    ss += df * df;
  }
  ss = wave_sum(ss);
  __shared__ float s_w[NWAVE];
  if (lane == 0) s_w[wv] = ss;
  __syncthreads();
  if (tid == 0) out[DIMS] = (s_w[0] + s_w[1] + s_w[2] + s_w[3]) * (1.0f / (float)DIMS);
}

extern "C" void kernel_launch(void* const* d_in, const int* in_sizes, int n_in,
                              void* d_out, int out_size, void* d_ws, size_t ws_size,
                              hipStream_t stream) {
  const float* iso = (const float*)d_in[0];
  const float* ca3 = (const float*)d_in[1];
  float* out = (float*)d_out;
  const int N = in_sizes[1] / DIMS;  // 262144

  // ws layout (floats):
  // accbuf[5*ACC_STRIDE] | cur0[1024] | part_l[NB] | part_acc[NB*1024]
  // | invnorm[N] | rowmeta float2[N] | qmat uint2[N*64]
  float* ws       = (float*)d_ws;
  float* accbuf   = ws;
  float* cur0     = ws + 5 * ACC_STRIDE;
  float* part_l   = cur0 + DIMS;
  float* part_acc = part_l + NB;
  float* invnorm  = part_acc + (size_t)NB * DIMS;
  float2* rowmeta = (float2*)(invnorm + N);
  uint2* qmat     = (uint2*)(invnorm + N + 2 * (size_t)N);

  const size_t need_bytes =
      (size_t)(5 * ACC_STRIDE + DIMS + NB + NB * DIMS + N) * 4 + (size_t)N * 8 + (size_t)N * 512;
  const bool use_i4 = (ws_size >= need_bytes);

  const int rows_per_block = N / NB;  // 256
  const int init_elems = 5 * ACC_STRIDE + DIMS;

  init_k<<<(init_elems + 255) / 256, 256, 0, stream>>>(iso, accbuf);
  if (use_i4) {
    pass_f32<1, 1><<<NB, TPB, 0, stream>>>(ca3, cur0, invnorm, qmat, rowmeta,
                                           accbuf, part_acc, part_l, rows_per_block);
    for (int s = 1; s < 5; ++s)
      pass_i4<<<NB, TPB, 0, stream>>>((const uint4*)qmat, cur0, rowmeta, accbuf,
                                      s, rows_per_block);
    final_k5<<<1, 64, 0, stream>>>(iso, cur0, accbuf, out);
  } else {
    for (int s = 0; s < 5; ++s) {
      if (s == 0)
        pass_f32<1, 0><<<NB, TPB, 0, stream>>>(ca3, cur0, invnorm, qmat, rowmeta,
                                               accbuf, part_acc, part_l, rows_per_block);
      else
        pass_f32<0, 0><<<NB, TPB, 0, stream>>>(ca3, cur0, invnorm, qmat, rowmeta,
                                               accbuf, part_acc, part_l, rows_per_block);
      combine_k<<<CB, 256, 0, stream>>>(part_acc, part_l, cur0);
    }
    final_k<<<1, 256, 0, stream>>>(iso, cur0, out);
  }
}

// Round 8
// 607.733 us; speedup vs baseline: 3.2110x; 3.2110x over previous
//
#include <hip/hip_runtime.h>

#define DIMS 1024
#define NB 1024         // f32 pass blocks
#define IB 512          // i4 pass blocks (2 blocks/CU)
#define TPB 256
#define NWAVE 4
#define CB 64           // fallback combine blocks
#define ACC_STRIDE 1088 // per-step accumulator stride (1024 dims + l + pad)

#if defined(__has_builtin)
#if __has_builtin(__builtin_amdgcn_sdot8)
#define HAVE_SDOT8 1
#endif
#endif
#ifndef HAVE_SDOT8
#define HAVE_SDOT8 0
#endif

__device__ __forceinline__ float wave_sum(float v) {
#pragma unroll
  for (int s = 32; s; s >>= 1) v += __shfl_xor(v, s, 64);
  return v;
}

__device__ __forceinline__ float wave_max(float v) {
#pragma unroll
  for (int s = 32; s; s >>= 1) v = fmaxf(v, __shfl_xor(v, s, 64));
  return v;
}

__device__ __forceinline__ int nib(unsigned int w, int i) {
  return (int)(w << (28 - 4 * i)) >> 28;
}

__device__ __forceinline__ int dot16(uint2 x, uint2 qc, int init) {
#if HAVE_SDOT8
  int t = __builtin_amdgcn_sdot8((int)x.x, (int)qc.x, init, false);
  return __builtin_amdgcn_sdot8((int)x.y, (int)qc.y, t, false);
#else
  int t = init;
#pragma unroll
  for (int i = 0; i < 8; ++i) t += __mul24(nib(x.x, i), nib(qc.x, i));
#pragma unroll
  for (int i = 0; i < 8; ++i) t += __mul24(nib(x.y, i), nib(qc.y, i));
  return t;
#endif
}

// encode 16 f32 (4x float4) -> 16 signed int4 nibbles (uint2); nibble order = c[0..15]
__device__ __forceinline__ uint2 enc_i4(const float4* xv, float scale) {
  unsigned int w[2];
#pragma unroll
  for (int h = 0; h < 2; ++h) {
    unsigned int a = 0;
#pragma unroll
    for (int jj = 0; jj < 2; ++jj) {
      float4 t = xv[h * 2 + jj];
      a |= ((unsigned int)((int)rintf(t.x * scale) & 0xF)) << (jj * 16 + 0);
      a |= ((unsigned int)((int)rintf(t.y * scale) & 0xF)) << (jj * 16 + 4);
      a |= ((unsigned int)((int)rintf(t.z * scale) & 0xF)) << (jj * 16 + 8);
      a |= ((unsigned int)((int)rintf(t.w * scale) & 0xF)) << (jj * 16 + 12);
    }
    w[h] = a;
  }
  return make_uint2(w[0], w[1]);
}

// ---------------- f32 pass: fixed-offset softmax, p = exp(sim-1) ----------
// STEP0: compute invnorm.  MODE: 0 = fallback (part_acc/part_l), 1 = quant-write + atomic acc0.
template <int STEP0, int MODE>
__global__ __launch_bounds__(TPB) void pass_f32(
    const float* __restrict__ ca3,
    const float* __restrict__ q,        // cur0 buffer
    float* __restrict__ invnorm,
    uint2* __restrict__ qmat,
    float2* __restrict__ rowmeta,
    float* __restrict__ accbuf,         // MODE=1: acc_0 (atomic)
    float* __restrict__ part_acc,       // MODE=0
    float* __restrict__ part_l,         // MODE=0
    int rows_per_block) {
  const int tid  = threadIdx.x;
  const int lane = tid & 63;
  const int wv   = tid >> 6;
  const int bid  = blockIdx.x;

  const float4* q4 = (const float4*)q;
  float4 qv[4];
  float qss = 0.f;
#pragma unroll
  for (int j = 0; j < 4; ++j) {
    float4 t = q4[j * 64 + lane];
    qv[j] = t;
    qss += t.x * t.x + t.y * t.y + t.z * t.z + t.w * t.w;
  }
  qss = wave_sum(qss);
  const float inv_qn = 1.0f / fmaxf(sqrtf(qss), 1e-8f);

  const int rpw = rows_per_block >> 2;
  const long long row0 = (long long)bid * rows_per_block + (long long)wv * rpw;

  float l = 0.f;
  float4 acc[4];
#pragma unroll
  for (int j = 0; j < 4; ++j) acc[j] = make_float4(0.f, 0.f, 0.f, 0.f);

  for (int r = 0; r < rpw; r += 2) {
    const long long rowA = row0 + r;
    const long long rowB = rowA + 1;
    const float4* xA4 = (const float4*)(ca3 + rowA * (long long)DIMS);
    const float4* xB4 = (const float4*)(ca3 + rowB * (long long)DIMS);
    float innA = 0.f, innB = 0.f;
    if (!STEP0) { innA = invnorm[rowA]; innB = invnorm[rowB]; }
    float4 xa[4], xb[4];
#pragma unroll
    for (int j = 0; j < 4; ++j) xa[j] = xA4[j * 64 + lane];
#pragma unroll
    for (int j = 0; j < 4; ++j) xb[j] = xB4[j * 64 + lane];

    float dA = 0.f, dB = 0.f, rnA = 0.f, rnB = 0.f, mxA = 0.f, mxB = 0.f;
#pragma unroll
    for (int j = 0; j < 4; ++j) {
      dA += xa[j].x * qv[j].x + xa[j].y * qv[j].y + xa[j].z * qv[j].z + xa[j].w * qv[j].w;
      dB += xb[j].x * qv[j].x + xb[j].y * qv[j].y + xb[j].z * qv[j].z + xb[j].w * qv[j].w;
      if (STEP0) {
        rnA += xa[j].x * xa[j].x + xa[j].y * xa[j].y + xa[j].z * xa[j].z + xa[j].w * xa[j].w;
        rnB += xb[j].x * xb[j].x + xb[j].y * xb[j].y + xb[j].z * xb[j].z + xb[j].w * xb[j].w;
      }
      if (MODE) {
        mxA = fmaxf(mxA, fmaxf(fmaxf(fabsf(xa[j].x), fabsf(xa[j].y)),
                               fmaxf(fabsf(xa[j].z), fabsf(xa[j].w))));
        mxB = fmaxf(mxB, fmaxf(fmaxf(fabsf(xb[j].x), fabsf(xb[j].y)),
                               fmaxf(fabsf(xb[j].z), fabsf(xb[j].w))));
      }
    }
    dA = wave_sum(dA);
    dB = wave_sum(dB);
    if (STEP0) {
      rnA = wave_sum(rnA);
      rnB = wave_sum(rnB);
      innA = 1.0f / fmaxf(sqrtf(rnA), 1e-8f);
      innB = 1.0f / fmaxf(sqrtf(rnB), 1e-8f);
      if (lane == 0) { invnorm[rowA] = innA; invnorm[rowB] = innB; }
    }
    if (MODE) {
      mxA = wave_max(mxA);
      mxB = wave_max(mxB);
      const float scA = 7.0f / fmaxf(mxA, 1e-20f);
      const float scB = 7.0f / fmaxf(mxB, 1e-20f);
      qmat[rowA * 64 + lane] = enc_i4(xa, scA);
      qmat[rowB * 64 + lane] = enc_i4(xb, scB);
      if (lane == 0) {
        const float isA = mxA * (1.0f / 7.0f);
        const float isB = mxB * (1.0f / 7.0f);
        rowmeta[rowA] = make_float2(isA * innA, isA);
        rowmeta[rowB] = make_float2(isB * innB, isB);
      }
    }
    const float pA = __expf(dA * innA * inv_qn - 1.0f);
    const float pB = __expf(dB * innB * inv_qn - 1.0f);
    l += pA + pB;
#pragma unroll
    for (int j = 0; j < 4; ++j) {
      acc[j].x += pA * xa[j].x + pB * xb[j].x;
      acc[j].y += pA * xa[j].y + pB * xb[j].y;
      acc[j].z += pA * xa[j].z + pB * xb[j].z;
      acc[j].w += pA * xa[j].w + pB * xb[j].w;
    }
  }

  // ---- block combine ----
  __shared__ float s_l[NWAVE];
  __shared__ float s_lin[NWAVE * DIMS];  // 16 KB
  if (lane == 0) s_l[wv] = l;
#pragma unroll
  for (int j = 0; j < 4; ++j)
    ((float4*)s_lin)[wv * (DIMS / 4) + j * 64 + lane] = acc[j];
  __syncthreads();
  float4 sum = ((float4*)s_lin)[tid];
#pragma unroll
  for (int w = 1; w < NWAVE; ++w) {
    float4 b = ((float4*)s_lin)[w * (DIMS / 4) + tid];
    sum.x += b.x; sum.y += b.y; sum.z += b.z; sum.w += b.w;
  }
  if (MODE) {
    atomicAdd(&accbuf[4 * tid + 0], sum.x);
    atomicAdd(&accbuf[4 * tid + 1], sum.y);
    atomicAdd(&accbuf[4 * tid + 2], sum.z);
    atomicAdd(&accbuf[4 * tid + 3], sum.w);
    if (tid == 0) atomicAdd(&accbuf[1024], s_l[0] + s_l[1] + s_l[2] + s_l[3]);
  } else {
    ((float4*)part_acc)[bid * (DIMS / 4) + tid] = sum;
    if (tid == 0) part_l[bid] = s_l[0] + s_l[1] + s_l[2] + s_l[3];
  }
}

// ---------------- int4 pass v2: LDS panel transpose, no per-row wave reduction ----------
// Block: 256 threads, rows_per_block rows = NPAN panels of 64 rows.
// Phase 1: thread (q=wv, r=lane) partial-dots chunk-slots 16q..16q+15 of row r.
// Wave 0 finishes: d -> p -> pai, all 64 rows in parallel lanes.
// Phase 2: thread (q=wv, c=lane) accumulates rows 16q..16q+15 into chunk c.
__global__ __launch_bounds__(TPB) void pass_i4(
    const uint2* __restrict__ qmat,     // row = 64 uint2 (512 B)
    const float* __restrict__ cur0,
    const float2* __restrict__ rowmeta, // {inv_scale*invnorm, inv_scale}
    float* __restrict__ accbuf,
    int step,                           // s in 1..4: read acc_0..s-1, write acc_s
    int rows_per_block) {
  const int tid  = threadIdx.x;
  const int lane = tid & 63;
  const int wv   = tid >> 6;
  const int bid  = blockIdx.x;

  __shared__ uint2 s_panel[64][64];   // 32 KB, col XOR-swizzled by (row&31)
  __shared__ uint2 s_q[64];
  __shared__ int   s_pd[NWAVE][64];
  __shared__ int   s_pai[64];
  __shared__ float s_qscale;
  __shared__ float s_lin[NWAVE * DIMS];  // 16 KB (epilogue)

  // ---- prologue (wave 0): reconstruct cur_step, quantize q into LDS ----
  if (wv == 0) {
    float c[16];
    float w0 = 1.0f;
    for (int t = 0; t < step; ++t) w0 *= 0.2f;
    const float4* c04 = (const float4*)cur0;
#pragma unroll
    for (int jj = 0; jj < 4; ++jj) {
      float4 t = c04[jj * 64 + lane];
      c[4 * jj + 0] = w0 * t.x; c[4 * jj + 1] = w0 * t.y;
      c[4 * jj + 2] = w0 * t.z; c[4 * jj + 3] = w0 * t.w;
    }
    for (int j = 0; j < step; ++j) {
      const float lj = accbuf[j * ACC_STRIDE + 1024];
      float coef = 0.8f / lj;
      for (int t = j; t < step - 1; ++t) coef *= 0.2f;
      const float4* aj = (const float4*)(accbuf + j * ACC_STRIDE);
#pragma unroll
      for (int jj = 0; jj < 4; ++jj) {
        float4 t = aj[jj * 64 + lane];
        c[4 * jj + 0] += coef * t.x; c[4 * jj + 1] += coef * t.y;
        c[4 * jj + 2] += coef * t.z; c[4 * jj + 3] += coef * t.w;
      }
    }
    float qss = 0.f, qmx = 0.f;
#pragma unroll
    for (int i = 0; i < 16; ++i) { qss += c[i] * c[i]; qmx = fmaxf(qmx, fabsf(c[i])); }
    qss = wave_sum(qss);
    qmx = wave_max(qmx);
    const float inv_qn = 1.0f / fmaxf(sqrtf(qss), 1e-8f);
    const float sq = 7.0f / fmaxf(qmx, 1e-20f);
    unsigned int qq0 = 0, qq1 = 0;
#pragma unroll
    for (int i = 0; i < 8; ++i)
      qq0 |= ((unsigned int)((int)rintf(c[i] * sq) & 0xF)) << (4 * i);
#pragma unroll
    for (int i = 0; i < 8; ++i)
      qq1 |= ((unsigned int)((int)rintf(c[8 + i] * sq) & 0xF)) << (4 * i);
    s_q[lane] = make_uint2(qq0, qq1);
    if (lane == 0) s_qscale = (qmx * (1.0f / 7.0f)) * inv_qn;
  }
  __syncthreads();
  const float qscale = s_qscale;

  const int NPAN = rows_per_block >> 6;
  const long long rowbase = (long long)bid * rows_per_block;
  const uint2* gq = qmat + rowbase * 64;

  float l_acc = 0.f;
  int acc_i[16];
#pragma unroll
  for (int i = 0; i < 16; ++i) acc_i[i] = 0;

  // preload panel 0 into regs (16 uint2 = coalesced)
  uint2 pf[16];
#pragma unroll
  for (int i = 0; i < 16; ++i) pf[i] = gq[i * 256 + tid];

  for (int p = 0; p < NPAN; ++p) {
    __syncthreads();  // prior phase-2 done reading s_panel
    // store prefetched panel: idx = i*256+tid -> r = i*4+wv (const per i), k = lane
#pragma unroll
    for (int i = 0; i < 16; ++i) {
      const int r = i * 4 + wv;
      s_panel[r][lane ^ (r & 31)] = pf[i];
    }
    // issue next panel's loads (hidden under compute)
    const int pn = (p + 1 < NPAN) ? (p + 1) : p;
    const long long pb = (long long)pn * 4096;
#pragma unroll
    for (int i = 0; i < 16; ++i) pf[i] = gq[pb + i * 256 + tid];
    __syncthreads();  // panel visible

    // phase 1: partial dot (quarter wv, row lane)
    {
      int pd = 0;
#pragma unroll
      for (int i = 0; i < 16; ++i) {
        const int c = wv * 16 + i;
        const uint2 x = s_panel[lane][c ^ (lane & 31)];
        pd = dot16(x, s_q[c], pd);
      }
      s_pd[wv][lane] = pd;
    }
    __syncthreads();

    if (tid < 64) {
      const int d = s_pd[0][tid] + s_pd[1][tid] + s_pd[2][tid] + s_pd[3][tid];
      const float2 mt = rowmeta[rowbase + (long long)p * 64 + tid];
      const float pw = __expf((float)d * mt.x * qscale - 1.0f);
      l_acc += pw;
      s_pai[tid] = (int)(pw * mt.y * 1048576.0f + 0.5f);
    }
    __syncthreads();

    // phase 2: thread (wv, c=lane) accumulates 16 rows of its quarter into chunk c
#pragma unroll
    for (int r2 = 0; r2 < 16; ++r2) {
      const int r = wv * 16 + r2;
      const int pai = s_pai[r];
      const uint2 x = s_panel[r][lane ^ (r & 31)];
#pragma unroll
      for (int i = 0; i < 8; ++i) acc_i[i]     += __mul24(pai, nib(x.x, i));
#pragma unroll
      for (int i = 0; i < 8; ++i) acc_i[8 + i] += __mul24(pai, nib(x.y, i));
    }
  }

  // ---- epilogue: 4 quarter-partials -> block sum -> atomic into acc_step ----
  const float ds = 9.5367431640625e-7f;  // 2^-20
#pragma unroll
  for (int j = 0; j < 4; ++j)
    ((float4*)s_lin)[wv * (DIMS / 4) + j * 64 + lane] =
        make_float4((float)acc_i[4 * j + 0] * ds, (float)acc_i[4 * j + 1] * ds,
                    (float)acc_i[4 * j + 2] * ds, (float)acc_i[4 * j + 3] * ds);
  __syncthreads();
  float4 sum = ((float4*)s_lin)[tid];
#pragma unroll
  for (int w = 1; w < NWAVE; ++w) {
    float4 b = ((float4*)s_lin)[w * (DIMS / 4) + tid];
    sum.x += b.x; sum.y += b.y; sum.z += b.z; sum.w += b.w;
  }
  float* accS = accbuf + step * ACC_STRIDE;
  atomicAdd(&accS[4 * tid + 0], sum.x);
  atomicAdd(&accS[4 * tid + 1], sum.y);
  atomicAdd(&accS[4 * tid + 2], sum.z);
  atomicAdd(&accS[4 * tid + 3], sum.w);
  if (wv == 0) {
    const float lt = wave_sum(l_acc);
    if (lane == 0) atomicAdd(&accS[1024], lt);
  }
}

// ---------------- init: zero acc buffers + DG thresholding into cur0 ----------------
__global__ void init_k(const float* __restrict__ iso, float* __restrict__ accbuf) {
  const int idx = blockIdx.x * blockDim.x + threadIdx.x;
  const int nacc = 5 * ACC_STRIDE;
  if (idx < nacc) accbuf[idx] = 0.f;
  else if (idx < nacc + DIMS) {
    const float v = iso[idx - nacc];
    accbuf[idx] = (v > 0.1f) ? v : 0.f;  // cur0 lives right after accbuf
  }
}

// ---------------- final (fast path): reconstruct cur_5, write out + mismatch ----------
__global__ __launch_bounds__(64) void final_k5(const float* __restrict__ iso,
                                               const float* __restrict__ cur0,
                                               const float* __restrict__ accbuf,
                                               float* __restrict__ out) {
  const int lane = threadIdx.x;
  float c[16];
  float w0 = 1.0f;
  for (int t = 0; t < 5; ++t) w0 *= 0.2f;
  const float4* c04 = (const float4*)cur0;
#pragma unroll
  for (int jj = 0; jj < 4; ++jj) {
    float4 t = c04[jj * 64 + lane];
    c[4 * jj + 0] = w0 * t.x; c[4 * jj + 1] = w0 * t.y;
    c[4 * jj + 2] = w0 * t.z; c[4 * jj + 3] = w0 * t.w;
  }
  for (int j = 0; j < 5; ++j) {
    const float lj = accbuf[j * ACC_STRIDE + 1024];
    float coef = 0.8f / lj;
    for (int t = j; t < 4; ++t) coef *= 0.2f;
    const float4* aj = (const float4*)(accbuf + j * ACC_STRIDE);
#pragma unroll
    for (int jj = 0; jj < 4; ++jj) {
      float4 t = aj[jj * 64 + lane];
      c[4 * jj + 0] += coef * t.x; c[4 * jj + 1] += coef * t.y;
      c[4 * jj + 2] += coef * t.z; c[4 * jj + 3] += coef * t.w;
    }
  }
  float ss = 0.f;
#pragma unroll
  for (int jj = 0; jj < 4; ++jj)
#pragma unroll
    for (int i = 0; i < 4; ++i) {
      const int d = 4 * (jj * 64 + lane) + i;
      const float cv = c[4 * jj + i];
      out[d] = cv;
      const float df = iso[d] - cv;
      ss += df * df;
    }
  ss = wave_sum(ss);
  if (lane == 0) out[DIMS] = ss * (1.0f / (float)DIMS);
}

// ---------------- fallback combine + final ----------------
__global__ __launch_bounds__(256) void combine_k(
    const float* __restrict__ part_acc,
    const float* __restrict__ part_l,
    float* __restrict__ cur) {
  const int tid  = threadIdx.x;
  const int lane = tid & 63;
  const int wv   = tid >> 6;
  __shared__ float s_w[NWAVE];
  float lz = 0.f;
  for (int p = tid; p < NB; p += 256) lz += part_l[p];
  lz = wave_sum(lz);
  if (lane == 0) s_w[wv] = lz;
  __syncthreads();
  const float invZ = 1.0f / (s_w[0] + s_w[1] + s_w[2] + s_w[3]);
  const int base = blockIdx.x * 16;
  const int d = tid & 15;
  const int g = tid >> 4;
  float a = 0.f;
  for (int p = g; p < NB; p += 16) a += part_acc[p * DIMS + base + d];
  __shared__ float s_a[16][17];
  s_a[g][d] = a;
  __syncthreads();
#pragma unroll
  for (int s = 8; s; s >>= 1) {
    if (g < s) s_a[g][d] += s_a[g + s][d];
    __syncthreads();
  }
  if (tid < 16) {
    const float retrieved = s_a[0][tid] * invZ;
    const float cc = cur[base + tid];
    cur[base + tid] = 0.8f * retrieved + 0.2f * cc;
  }
}

__global__ __launch_bounds__(256) void final_k(const float* __restrict__ iso,
                                               const float* __restrict__ cur,
                                               float* __restrict__ out) {
  const int tid  = threadIdx.x;
  const int lane = tid & 63;
  const int wv   = tid >> 6;
  float ss = 0.f;
  for (int d = tid; d < DIMS; d += 256) {
    const float c = cur[d];
    out[d] = c;
    const float df = iso[d] - c;
    ss += df * df;
  }
  ss = wave_sum(ss);
  __shared__ float s_w[NWAVE];
  if (lane == 0) s_w[wv] = ss;
  __syncthreads();
  if (tid == 0) out[DIMS] = (s_w[0] + s_w[1] + s_w[2] + s_w[3]) * (1.0f / (float)DIMS);
}

extern "C" void kernel_launch(void* const* d_in, const int* in_sizes, int n_in,
                              void* d_out, int out_size, void* d_ws, size_t ws_size,
                              hipStream_t stream) {
  const float* iso = (const float*)d_in[0];
  const float* ca3 = (const float*)d_in[1];
  float* out = (float*)d_out;
  const int N = in_sizes[1] / DIMS;  // 262144

  // ws layout (floats):
  // accbuf[5*ACC_STRIDE] | cur0[1024] | part_l[NB] | part_acc[NB*1024]
  // | invnorm[N] | rowmeta float2[N] | qmat uint2[N*64]
  float* ws       = (float*)d_ws;
  float* accbuf   = ws;
  float* cur0     = ws + 5 * ACC_STRIDE;
  float* part_l   = cur0 + DIMS;
  float* part_acc = part_l + NB;
  float* invnorm  = part_acc + (size_t)NB * DIMS;
  float2* rowmeta = (float2*)(invnorm + N);
  uint2* qmat     = (uint2*)(invnorm + N + 2 * (size_t)N);

  const size_t need_bytes =
      (size_t)(5 * ACC_STRIDE + DIMS + NB + NB * DIMS + N) * 4 + (size_t)N * 8 + (size_t)N * 512;
  const bool use_i4 = (ws_size >= need_bytes);

  const int init_elems = 5 * ACC_STRIDE + DIMS;
  init_k<<<(init_elems + 255) / 256, 256, 0, stream>>>(iso, accbuf);

  if (use_i4) {
    pass_f32<1, 1><<<NB, TPB, 0, stream>>>(ca3, cur0, invnorm, qmat, rowmeta,
                                           accbuf, part_acc, part_l, N / NB);
    for (int s = 1; s < 5; ++s)
      pass_i4<<<IB, TPB, 0, stream>>>(qmat, cur0, rowmeta, accbuf, s, N / IB);
    final_k5<<<1, 64, 0, stream>>>(iso, cur0, accbuf, out);
  } else {
    for (int s = 0; s < 5; ++s) {
      if (s == 0)
        pass_f32<1, 0><<<NB, TPB, 0, stream>>>(ca3, cur0, invnorm, qmat, rowmeta,
                                               accbuf, part_acc, part_l, N / NB);
      else
        pass_f32<0, 0><<<NB, TPB, 0, stream>>>(ca3, cur0, invnorm, qmat, rowmeta,
                                               accbuf, part_acc, part_l, N / NB);
      combine_k<<<CB, 256, 0, stream>>>(part_acc, part_l, cur0);
    }
    final_k<<<1, 256, 0, stream>>>(iso, cur0, out);
  }
}